// Round 9
// baseline (168.951 us; speedup 1.0000x reference)
//
#include <hip/hip_runtime.h>
#include <hip/hip_bf16.h>

#define B 8
#define T 1024
#define E 128
#define H 8
#define DH 16
#define E3 384

typedef __attribute__((ext_vector_type(8))) short short8;
typedef __attribute__((ext_vector_type(4))) short short4s;
typedef __attribute__((ext_vector_type(4))) float f32x4;

// fp32 -> bf16 (round-to-nearest-even), bit pattern in a short
static __device__ inline short bf16s(float x) {
    union { float f; unsigned u; } v; v.f = x;
    unsigned r = v.u + 0x7fffu + ((v.u >> 16) & 1u);
    return (short)(r >> 16);
}

// exp2 via the HW transcendental (1 inst)
#if __has_builtin(__builtin_amdgcn_exp2f)
static __device__ inline float fexp2(float x) { return __builtin_amdgcn_exp2f(x); }
#else
static __device__ inline float fexp2(float x) { return __builtin_exp2f(x); }
#endif

// pack two fp32 into bf16x2 via v_cvt_pk_bf16_f32
static __device__ inline __hip_bfloat162 pk2(float a, float b) {
    float2 t; t.x = a; t.y = b;
    return __float22bfloat162_rn(t);
}

#define QSCALE 0.36067376022224085f   /* 0.25 * log2(e) */

// ---------------------------------------------------------------------------
// Kernel 1: prep = pack_win (blocks 0..191) + fuse_weights (blocks 192..255).
//   Wp_* : win packed to bf16 K=256 complex layout.
//   Wfp_*: (wt@wout) packed likewise; bf = wt@bout + bt (fp32).
// ---------------------------------------------------------------------------
__global__ __launch_bounds__(256) void prep_kernel(
    const float* __restrict__ win_re, const float* __restrict__ win_im,
    const float* __restrict__ wout_re, const float* __restrict__ wout_im,
    const float* __restrict__ bout_re, const float* __restrict__ bout_im,
    const float* __restrict__ wt_re,   const float* __restrict__ wt_im,
    const float* __restrict__ bt_re,   const float* __restrict__ bt_im,
    short* __restrict__ Wp_re, short* __restrict__ Wp_im,
    short* __restrict__ Wfp_re, short* __restrict__ Wfp_im,
    float* __restrict__ bf_re, float* __restrict__ bf_im)
{
    int bid = blockIdx.x;
    if (bid < 192) {
        int idx = bid * 256 + threadIdx.x;   // [0, 384*128)
        int j = idx >> 7, e = idx & 127;
        float wr = win_re[idx], wi = win_im[idx];
        Wp_re[j*256 + e]       = bf16s(wr);
        Wp_re[j*256 + 128 + e] = bf16s(-wi);
        Wp_im[j*256 + e]       = bf16s(wi);
        Wp_im[j*256 + 128 + e] = bf16s(wr);
        return;
    }
    int idx = (bid - 192) * 256 + threadIdx.x;   // [0, E*E)
    int j = idx >> 7, e = idx & 127;
    float ar = 0.f, ai = 0.f;
    for (int m = 0; m < E; ++m) {
        float tr = wt_re[j*E+m], ti = wt_im[j*E+m];
        float pr = wout_re[m*E+e], pi = wout_im[m*E+e];
        ar += tr*pr - ti*pi;
        ai += tr*pi + ti*pr;
    }
    Wfp_re[j*256 + e]       = bf16s(ar);
    Wfp_re[j*256 + 128 + e] = bf16s(-ai);
    Wfp_im[j*256 + e]       = bf16s(ai);
    Wfp_im[j*256 + 128 + e] = bf16s(ar);
    if (idx < E) {
        float br = bt_re[idx], bi = bt_im[idx];
        for (int m = 0; m < E; ++m) {
            float tr = wt_re[idx*E+m], ti = wt_im[idx*E+m];
            br += tr*bout_re[m] - ti*bout_im[m];
            bi += tr*bout_im[m] + ti*bout_re[m];
        }
        bf_re[idx] = br; bf_im[idx] = bi;
    }
}

// ---------------------------------------------------------------------------
// Kernel 2: MFMA QKV projection; X staged ONCE per block via LDS (was 4x
// redundant per-wave gather). Grid 1024: id = ttile*2 + half (re/im).
//   Qpk/Kpk : bf16 [bh][t][32]; q scaled 0.25*log2(e) (attn uses exp2)
//   Vtre/Vtim: bf16 [bh][dh][T] transposed + pi-interleaved per 32-t block
// ---------------------------------------------------------------------------
#define XSTR 280   /* LDS row stride in shorts: 560B, 16B-aligned */
__global__ __launch_bounds__(256) void qkv_mfma_kernel(
    const float* __restrict__ x_re, const float* __restrict__ x_im,
    const short* __restrict__ Wp_re, const short* __restrict__ Wp_im,
    const float* __restrict__ bin_re, const float* __restrict__ bin_im,
    short* __restrict__ Qpk, short* __restrict__ Kpk,
    short* __restrict__ Vtre, short* __restrict__ Vtim)
{
    __shared__ __align__(16) short Xl[16 * XSTR];   // [t][k] bf16, k=reim*128+e

    int tid  = threadIdx.x;
    int wave = tid >> 6, lane = tid & 63;
    int col  = lane & 15, quad = lane >> 4;
    int id = blockIdx.x;               // [0, 1024)
    int ttile = id >> 1;
    int is_im = id & 1;
    int b  = ttile >> 6;
    int t0 = (ttile & 63) * 16;
    int tb = t0 + col;

    // ---- stage X: thread = (k-pair p, t-half). rows k=2p,2p+1; 8 t's ----
    {
        int p     = tid & 127;           // k-pair index
        int thalf = tid >> 7;            // 0/1 -> t0.. / t0+8..
        const float* xs = (p < 64) ? x_re : x_im;
        int eA = (p < 64) ? 2*p : 2*p - 128;
        const float* rowA = &xs[((long)(b*E + eA))*T + t0 + thalf*8];
        const float* rowB = rowA + T;
        f32x4 a0 = *(const f32x4*)rowA;
        f32x4 a1 = *(const f32x4*)(rowA + 4);
        f32x4 b0 = *(const f32x4*)rowB;
        f32x4 b1 = *(const f32x4*)(rowB + 4);
        short* base = &Xl[(thalf*8)*XSTR + 2*p];
        #pragma unroll
        for (int tt = 0; tt < 4; ++tt)
            *(__hip_bfloat162*)(base + tt*XSTR) = pk2(a0[tt], b0[tt]);
        #pragma unroll
        for (int tt = 0; tt < 4; ++tt)
            *(__hip_bfloat162*)(base + (4+tt)*XSTR) = pk2(a1[tt], b1[tt]);
    }
    __syncthreads();

    // fragment read: B[n=col(t)][k=quad*8+jj] per kt
    short8 xf[8];
    #pragma unroll
    for (int kt = 0; kt < 8; ++kt)
        xf[kt] = *(const short8*)&Xl[col*XSTR + kt*32 + quad*8];

    const short* Wsel = is_im ? Wp_im : Wp_re;
    const float* bias = is_im ? bin_im : bin_re;
    const f32x4 zero = {0.f,0.f,0.f,0.f};

    for (int ni = 0; ni < 6; ++ni) {
        int jt = wave * 6 + ni;            // [0,24): which*8 + h
        const short* wrow = &Wsel[(jt*16 + col)*256 + quad*8];
        f32x4 acc = zero;
        #pragma unroll
        for (int kt = 0; kt < 8; ++kt) {
            short8 af = *(const short8*)(wrow + kt*32);
            acc = __builtin_amdgcn_mfma_f32_16x16x32_bf16(af, xf[kt], acc, 0, 0, 0);
        }
        int which = jt >> 3;               // 0 q, 1 k, 2 v
        int h = jt & 7;
        float scale = (which == 0) ? QSCALE : 1.0f;
        f32x4 res;
        #pragma unroll
        for (int r = 0; r < 4; ++r) {
            int jg = which*128 + h*16 + quad*4 + r;
            res[r] = (acc[r] + bias[jg]) * scale;
        }
        long bh = b*H + h;
        if (which == 2) {
            // V transposed + pi-interleaved: Vt[bh][dh][blk*32 + pos]
            short* vt = is_im ? Vtim : Vtre;
            int tloc = tb & 31, tblk = tb & ~31;
            int u  = tloc & 15;
            int kk = (u >> 2)*8 + (u & 3) + ((tloc >= 16) ? 4 : 0);
            #pragma unroll
            for (int r = 0; r < 4; ++r)
                vt[(bh*DH + quad*4 + r)*T + tblk + kk] = bf16s(res[r]);
        } else {
            short* qk = (which == 0) ? Qpk : Kpk;
            short4s pk;
            __hip_bfloat162* pp = (__hip_bfloat162*)&pk;
            pp[0] = pk2(res[0], res[1]);
            pp[1] = pk2(res[2], res[3]);
            *(short4s*)&qk[(bh*T + tb)*32 + is_im*16 + quad*4] = pk;
        }
    }
}

// ---------------------------------------------------------------------------
// Kernel 3: MFMA flash attention -- no LDS, in-register P, 32 queries/wave.
// (unchanged from round 8)
// ---------------------------------------------------------------------------
__global__ __launch_bounds__(256) void attn_mfma_kernel(
    const short* __restrict__ Qpk, const short* __restrict__ Kpk,
    const short* __restrict__ Vtre, const short* __restrict__ Vtim,
    short* __restrict__ Opk)
{
    int id   = blockIdx.x;
    int bh   = id & 63;
    int q0   = (id >> 6) * 128;
    int tid  = threadIdx.x;
    int wave = tid >> 6;
    int lane = tid & 63;
    int col  = lane & 15;
    int quad = lane >> 4;

    long kq_base = (long)bh * T * 32;
    int qbase = q0 + wave * 32;

    short8 qfA = *(const short8*)&Qpk[kq_base + (long)(qbase + col)*32 + quad*8];
    short8 qfB = *(const short8*)&Qpk[kq_base + (long)(qbase + 16 + col)*32 + quad*8];

    const short* kp  = &Kpk[kq_base + col*32 + quad*8];
    const short* vrp = &Vtre[(long)bh*DH*T + (long)col*T + quad*8];
    const short* vip = &Vtim[(long)bh*DH*T + (long)col*T + quad*8];

    short8 ones;
    #pragma unroll
    for (int i = 0; i < 8; ++i) ones[i] = (short)0x3F80;   // bf16 1.0

    f32x4 oAr = {0,0,0,0}, oAi = {0,0,0,0}, lA = {0,0,0,0};
    f32x4 oBr = {0,0,0,0}, oBi = {0,0,0,0}, lB = {0,0,0,0};
    const f32x4 zero = {0.f,0.f,0.f,0.f};

    short8 kf0 = *(const short8*)kp;
    short8 kf1 = *(const short8*)(kp + 512);
    short8 vr  = *(const short8*)vrp;
    short8 vi  = *(const short8*)vip;
    kp += 1024; vrp += 32; vip += 32;

    for (int i = 0; i < 32; ++i) {
        short8 kf0n = *(const short8*)kp;
        short8 kf1n = *(const short8*)(kp + 512);
        short8 vrn  = *(const short8*)vrp;
        short8 vin  = *(const short8*)vip;
        kp += 1024; vrp += 32; vip += 32;

        f32x4 sA0 = __builtin_amdgcn_mfma_f32_16x16x32_bf16(kf0, qfA, zero, 0, 0, 0);
        f32x4 sA1 = __builtin_amdgcn_mfma_f32_16x16x32_bf16(kf1, qfA, zero, 0, 0, 0);
        f32x4 sB0 = __builtin_amdgcn_mfma_f32_16x16x32_bf16(kf0, qfB, zero, 0, 0, 0);
        f32x4 sB1 = __builtin_amdgcn_mfma_f32_16x16x32_bf16(kf1, qfB, zero, 0, 0, 0);

        short8 pfA, pfB;
        {
            __hip_bfloat162* pa = (__hip_bfloat162*)&pfA;
            pa[0] = pk2(fexp2(sA0[0]), fexp2(sA0[1]));
            pa[1] = pk2(fexp2(sA0[2]), fexp2(sA0[3]));
            pa[2] = pk2(fexp2(sA1[0]), fexp2(sA1[1]));
            pa[3] = pk2(fexp2(sA1[2]), fexp2(sA1[3]));
            __hip_bfloat162* pb = (__hip_bfloat162*)&pfB;
            pb[0] = pk2(fexp2(sB0[0]), fexp2(sB0[1]));
            pb[1] = pk2(fexp2(sB0[2]), fexp2(sB0[3]));
            pb[2] = pk2(fexp2(sB1[0]), fexp2(sB1[1]));
            pb[3] = pk2(fexp2(sB1[2]), fexp2(sB1[3]));
        }

        oAr = __builtin_amdgcn_mfma_f32_16x16x32_bf16(vr, pfA, oAr, 0, 0, 0);
        oAi = __builtin_amdgcn_mfma_f32_16x16x32_bf16(vi, pfA, oAi, 0, 0, 0);
        lA  = __builtin_amdgcn_mfma_f32_16x16x32_bf16(ones, pfA, lA, 0, 0, 0);
        oBr = __builtin_amdgcn_mfma_f32_16x16x32_bf16(vr, pfB, oBr, 0, 0, 0);
        oBi = __builtin_amdgcn_mfma_f32_16x16x32_bf16(vi, pfB, oBi, 0, 0, 0);
        lB  = __builtin_amdgcn_mfma_f32_16x16x32_bf16(ones, pfB, lB, 0, 0, 0);

        kf0 = kf0n; kf1 = kf1n; vr = vrn; vi = vin;
    }

    int b = bh >> 3, h = bh & 7;
    float invA = 1.0f / lA[0];
    float invB = 1.0f / lB[0];

    long orowA = ((long)(b*T + qbase + col))*256 + h*16 + quad*4;
    {
        short4s pr, pi_;
        __hip_bfloat162* a = (__hip_bfloat162*)&pr;
        a[0] = pk2(oAr[0]*invA, oAr[1]*invA);
        a[1] = pk2(oAr[2]*invA, oAr[3]*invA);
        __hip_bfloat162* c = (__hip_bfloat162*)&pi_;
        c[0] = pk2(oAi[0]*invA, oAi[1]*invA);
        c[1] = pk2(oAi[2]*invA, oAi[3]*invA);
        *(short4s*)&Opk[orowA]       = pr;
        *(short4s*)&Opk[orowA + 128] = pi_;
    }
    long orowB = orowA + 16L*256;
    {
        short4s pr, pi_;
        __hip_bfloat162* a = (__hip_bfloat162*)&pr;
        a[0] = pk2(oBr[0]*invB, oBr[1]*invB);
        a[1] = pk2(oBr[2]*invB, oBr[3]*invB);
        __hip_bfloat162* c = (__hip_bfloat162*)&pi_;
        c[0] = pk2(oBi[0]*invB, oBi[1]*invB);
        c[1] = pk2(oBi[2]*invB, oBi[3]*invB);
        *(short4s*)&Opk[orowB]       = pr;
        *(short4s*)&Opk[orowB + 128] = pi_;
    }
}

// ---------------------------------------------------------------------------
// Kernel 4: MFMA output projection (unchanged).
// ---------------------------------------------------------------------------
__global__ __launch_bounds__(256) void outproj_mfma_kernel(
    const short* __restrict__ Opk,
    const short* __restrict__ Wfp_re, const short* __restrict__ Wfp_im,
    const float* __restrict__ bf_re, const float* __restrict__ bf_im,
    float* __restrict__ out)
{
    int tid  = threadIdx.x;
    int wave = tid >> 6, lane = tid & 63;
    int col  = lane & 15, quad = lane >> 4;
    int ttile = blockIdx.x;            // [0,512)
    int b  = ttile >> 6;
    int tb = (ttile & 63) * 16 + col;
    long trow = (long)b*T + tb;

    short8 xf[8];
    #pragma unroll
    for (int kt = 0; kt < 8; ++kt)
        xf[kt] = *(const short8*)&Opk[trow*256 + kt*32 + quad*8];

    const f32x4 zero = {0.f,0.f,0.f,0.f};
    #pragma unroll
    for (int ni = 0; ni < 4; ++ni) {
        int nt = wave * 4 + ni;            // [0,16)
        int is_im = nt >= 8;
        int jt = is_im ? nt - 8 : nt;      // [0,8)
        const short* Wsel = is_im ? Wfp_im : Wfp_re;
        const short* wrow = &Wsel[(jt*16 + col)*256 + quad*8];
        f32x4 acc = zero;
        #pragma unroll
        for (int kt = 0; kt < 8; ++kt) {
            short8 af = *(const short8*)(wrow + kt*32);
            acc = __builtin_amdgcn_mfma_f32_16x16x32_bf16(af, xf[kt], acc, 0, 0, 0);
        }
        const float* bias = is_im ? bf_im : bf_re;
        long part = is_im ? (long)B*E*T : 0;
        #pragma unroll
        for (int r = 0; r < 4; ++r) {
            int j = jt*16 + quad*4 + r;
            out[part + ((long)(b*E + j))*T + tb] = acc[r] + bias[j];
        }
    }
}

// ---------------------------------------------------------------------------
extern "C" void kernel_launch(void* const* d_in, const int* in_sizes, int n_in,
                              void* d_out, int out_size, void* d_ws, size_t ws_size,
                              hipStream_t stream)
{
    const float* x_re    = (const float*)d_in[0];
    const float* x_im    = (const float*)d_in[1];
    const float* win_re  = (const float*)d_in[2];
    const float* win_im  = (const float*)d_in[3];
    const float* bin_re  = (const float*)d_in[4];
    const float* bin_im  = (const float*)d_in[5];
    const float* wout_re = (const float*)d_in[6];
    const float* wout_im = (const float*)d_in[7];
    const float* bout_re = (const float*)d_in[8];
    const float* bout_im = (const float*)d_in[9];
    const float* wt_re   = (const float*)d_in[10];
    const float* wt_im   = (const float*)d_in[11];
    const float* bt_re   = (const float*)d_in[12];
    const float* bt_im   = (const float*)d_in[13];
    float* out = (float*)d_out;

    // workspace layout (shorts/floats)
    short* Qpk  = (short*)d_ws;                       // 64*1024*32 = 2M shorts
    short* Kpk  = Qpk + (long)B*H*T*32;
    short* Vtre = Kpk + (long)B*H*T*32;               // 64*16*1024 = 1M shorts
    short* Vtim = Vtre + (long)B*H*DH*T;
    short* Opk  = Vtim + (long)B*H*DH*T;              // 8*1024*256 = 2M shorts
    short* Wp_re  = Opk + (long)B*T*256;
    short* Wp_im  = Wp_re + E3*256;
    short* Wfp_re = Wp_im + E3*256;
    short* Wfp_im = Wfp_re + E*256;
    float* bf_re  = (float*)(Wfp_im + E*256);
    float* bf_im  = bf_re + E;

    prep_kernel<<<dim3(256), dim3(256), 0, stream>>>(
        win_re, win_im, wout_re, wout_im, bout_re, bout_im,
        wt_re, wt_im, bt_re, bt_im,
        Wp_re, Wp_im, Wfp_re, Wfp_im, bf_re, bf_im);

    qkv_mfma_kernel<<<dim3(T*B/16*2), dim3(256), 0, stream>>>(
        x_re, x_im, Wp_re, Wp_im, bin_re, bin_im,
        Qpk, Kpk, Vtre, Vtim);

    attn_mfma_kernel<<<dim3(8 * 64), dim3(256), 0, stream>>>(
        Qpk, Kpk, Vtre, Vtim, Opk);

    outproj_mfma_kernel<<<dim3(T*B/16), dim3(256), 0, stream>>>(
        Opk, Wfp_re, Wfp_im, bf_re, bf_im, out);
}